// Round 1
// baseline (120.203 us; speedup 1.0000x reference)
//
#include <hip/hip_runtime.h>
#include <stdint.h>

// FFM: B=4096, F=20 fields x S=500 feats, K=16.
// E[b,g,i,k] = sum_s x[b,i*500+s] * v[g,i*500+s,k]   (20 GEMMs [B,500]x[500,320])
// out[b] = x[b,:]@w + sum_{i<j} sum_k E[b,j,i,k]*E[b,i,j,k]

#define NF 20
#define FS 500
#define TFEAT 10000
#define KD 16
#define NC 320          // NF*KD, GEMM N
#define KP 512          // K padded to mult of 64
#define NB 4096

typedef __bf16 bf16x8 __attribute__((ext_vector_type(8)));
typedef __bf16 bf16x4 __attribute__((ext_vector_type(4)));
typedef __bf16 bf16x2 __attribute__((ext_vector_type(2)));
typedef float  f32x4  __attribute__((ext_vector_type(4)));
typedef unsigned int u32x4 __attribute__((ext_vector_type(4)));

typedef __attribute__((address_space(1))) const void* as1cv;
typedef __attribute__((address_space(3))) void* as3v;

__device__ inline void gload_lds16(const void* g, void* l) {
  // 16B per lane, LDS dest = wave-uniform base + lane*16 (linear)
  __builtin_amdgcn_global_load_lds((as1cv)g, (as3v)l, 16, 0, 0);
}

// ---------------- prep: Vt[i][n][kk] = v[g, i*500+kk, k], n=g*16+k, kk<512 (0-padded)
__global__ __launch_bounds__(256) void prep_vt(const float* __restrict__ v,
                                               __bf16* __restrict__ Vt) {
  __shared__ float lv[FS * 17];  // +1 pad breaks bank conflicts on transposed read
  const int i = blockIdx.x / NF;
  const int g = blockIdx.x % NF;
  const int t = threadIdx.x;
  const int k = t & 15, sb = t >> 4;
  const float* vb = v + ((size_t)g * TFEAT + (size_t)i * FS) * KD;
  for (int it = 0; it < 32; ++it) {
    int s = it * 16 + sb;
    if (s < FS) lv[s * 17 + k] = vb[(size_t)s * KD + k];
  }
  __syncthreads();
  __bf16* out = Vt + ((size_t)(i * NC + g * 16)) * KP;
  for (int r = 0; r < 16; ++r) {
    int s0 = 2 * t, s1 = 2 * t + 1;
    bf16x2 pr;
    pr[0] = (s0 < FS) ? (__bf16)lv[s0 * 17 + r] : (__bf16)0.f;
    pr[1] = (s1 < FS) ? (__bf16)lv[s1 * 17 + r] : (__bf16)0.f;
    *(bf16x2*)(out + (size_t)r * KP + 2 * t) = pr;
  }
}

// ---------------- K1: per-field GEMM + fused linear partial
// grid = NF * tiles, block 256 (4 waves as 2x2), BM=128, BN=320, BK=64
__global__ __launch_bounds__(256, 2) void k1_gemm(
    const float* __restrict__ x, const float* __restrict__ w,
    const __bf16* __restrict__ Vt, __bf16* __restrict__ E,
    float* __restrict__ lin, int chunk_base, int tiles) {
  __shared__ __align__(16) __bf16 As[128 * 72];   // [row][72] (pad 64->72)
  __shared__ __align__(16) __bf16 Bs[NC * 64];    // [n][64], 16B-chunk XOR-swizzled
  __shared__ float lin_s[128];

  const int bx = blockIdx.x;
  const int i  = bx / tiles;        // field
  const int tb = bx % tiles;        // batch tile
  const int tid = threadIdx.x;
  const int lane = tid & 63, wid = tid >> 6;
  const int wm = wid >> 1, wn = wid & 1;

  if (tid < 128) lin_s[tid] = 0.f;

  const int b0 = chunk_base + tb * 128;           // global batch row base
  const int arow = tid >> 4;                      // 0..15
  const int k4 = (tid & 15) * 4;
  const float* xbase = x + (size_t)b0 * TFEAT + i * FS;
  const float* wbase = w + i * FS;

  const int nrow_base = wid * 80;                 // B-stage: 80 rows/wave
  const int lrow = lane >> 3;                     // 0..7
  const int lswz = ((lane & 7) ^ lrow) * 8;       // inverse-swizzled k-offset (elems)
  const __bf16* VtB = Vt + (size_t)i * NC * KP;

  float lp[8];
#pragma unroll
  for (int p = 0; p < 8; ++p) lp[p] = 0.f;
  f32x4 acc[4][10];
#pragma unroll
  for (int m = 0; m < 4; ++m)
#pragma unroll
    for (int nf = 0; nf < 10; ++nf) acc[m][nf] = (f32x4){0.f, 0.f, 0.f, 0.f};

  for (int t = 0; t < 8; ++t) {
    const int kk0 = t * 64;
    __syncthreads();
    // --- stage B: Vt[i][n][kk0..kk0+63] -> Bs[n][64], src pre-swizzled so that
    // physical 16B chunk pc holds logical chunk pc ^ (n&7)
#pragma unroll
    for (int jj = 0; jj < 10; ++jj) {
      int n = nrow_base + jj * 8 + lrow;
      gload_lds16(VtB + (size_t)n * KP + kk0 + lswz,
                  (void*)(Bs + (size_t)(nrow_base + jj * 8) * 64));
    }
    // --- stage A: x f32 -> bf16, + linear partial
#pragma unroll
    for (int p = 0; p < 8; ++p) {
      int row = p * 16 + arow;
      int kk = kk0 + k4;
      f32x4 xv = (f32x4){0.f, 0.f, 0.f, 0.f};
      if (kk < FS) {
        xv = *(const f32x4*)(xbase + (size_t)row * TFEAT + kk);
        f32x4 wv = *(const f32x4*)(wbase + kk);
        lp[p] += xv[0] * wv[0] + xv[1] * wv[1] + xv[2] * wv[2] + xv[3] * wv[3];
      }
      bf16x4 hv;
      hv[0] = (__bf16)xv[0]; hv[1] = (__bf16)xv[1];
      hv[2] = (__bf16)xv[2]; hv[3] = (__bf16)xv[3];
      *(bf16x4*)(As + (size_t)row * 72 + k4) = hv;
    }
    __syncthreads();
    // --- MFMA: 2 k32 substeps, wave tile 64x160
#pragma unroll
    for (int ks = 0; ks < 2; ++ks) {
      bf16x8 af[4];
#pragma unroll
      for (int m = 0; m < 4; ++m) {
        int row = wm * 64 + m * 16 + (lane & 15);
        af[m] = *(const bf16x8*)(As + (size_t)row * 72 + ks * 32 + (lane >> 4) * 8);
      }
#pragma unroll
      for (int nf = 0; nf < 10; ++nf) {
        int n = wn * 160 + nf * 16 + (lane & 15);
        int pc = (ks * 4 + (lane >> 4)) ^ (n & 7);
        bf16x8 bf = *(const bf16x8*)(Bs + (size_t)n * 64 + pc * 8);
#pragma unroll
        for (int m = 0; m < 4; ++m)
          acc[m][nf] = __builtin_amdgcn_mfma_f32_16x16x32_bf16(af[m], bf, acc[m][nf], 0, 0, 0);
      }
    }
  }

  // --- epilogue: E[b_local][i*320+n] (bf16), C/D layout: col=lane&15, row=(lane>>4)*4+r
  const int lrow4 = (lane >> 4) * 4, lcol = lane & 15;
#pragma unroll
  for (int m = 0; m < 4; ++m) {
#pragma unroll
    for (int nf = 0; nf < 10; ++nf) {
      int n = wn * 160 + nf * 16 + lcol;
#pragma unroll
      for (int r = 0; r < 4; ++r) {
        int bl = tb * 128 + wm * 64 + m * 16 + lrow4 + r;  // chunk-local row
        E[(size_t)bl * (NF * NC) + i * NC + n] = (__bf16)acc[m][nf][r];
      }
    }
  }
  // --- linear partial reduce
#pragma unroll
  for (int p = 0; p < 8; ++p) atomicAdd(&lin_s[p * 16 + arow], lp[p]);
  __syncthreads();
  if (tid < 128) atomicAdd(&lin[b0 + tid], lin_s[tid]);
}

// ---------------- K2: pair reduction, 1 wave per batch row
__global__ __launch_bounds__(256) void k2_pair(
    const __bf16* __restrict__ E, const float* __restrict__ lin,
    float* __restrict__ out, int chunk_base) {
  __shared__ __align__(16) unsigned shw[4][3200];  // 12.8KB per wave
  const int tid = threadIdx.x, lane = tid & 63, wid = tid >> 6;
  const int bl = blockIdx.x * 4 + wid;             // chunk-local row
  const unsigned* src = (const unsigned*)(E + (size_t)bl * (NF * NC));
  for (int it = 0; it < 13; ++it) {
    int idx = it * 64 + lane;                      // 16B units
    if (idx < 800) {
      u32x4 val = *(const u32x4*)(src + (size_t)idx * 4);
      *(u32x4*)&shw[wid][idx * 4] = val;
    }
  }
  __syncthreads();
  const __bf16* sh = (const __bf16*)shw[wid];
  const int k = lane & 15, g = lane >> 4;
  float sum = 0.f;
  for (int i = g; i < NF; i += 4)
    for (int j = i + 1; j < NF; ++j)
      sum += (float)sh[i * NC + j * 16 + k] * (float)sh[j * NC + i * 16 + k];
#pragma unroll
  for (int off = 32; off; off >>= 1) sum += __shfl_xor(sum, off);
  if (lane == 0) {
    int bg = chunk_base + bl;
    out[bg] = lin[bg] + sum;
  }
}

extern "C" void kernel_launch(void* const* d_in, const int* in_sizes, int n_in,
                              void* d_out, int out_size, void* d_ws, size_t ws_size,
                              hipStream_t stream) {
  const float* x = (const float*)d_in[0];
  const float* w = (const float*)d_in[1];
  const float* v = (const float*)d_in[2];
  float* out = (float*)d_out;
  char* ws = (char*)d_ws;

  __bf16* Vt = (__bf16*)ws;                                // 20*320*512*2 = 6,553,600 B
  float* lin = (float*)(ws + 6553600);                     // 16,384 B
  __bf16* E  = (__bf16*)(ws + 6553600 + 16384);            // Bc*6400*2 B

  size_t eavail = (ws_size > 6569984) ? ws_size - 6569984 : 0;
  int Bc = NB;
  while (Bc > 128 && (size_t)Bc * (NF * NC) * 2 > eavail) Bc >>= 1;

  hipMemsetAsync(lin, 0, NB * sizeof(float), stream);
  prep_vt<<<NF * NF, 256, 0, stream>>>(v, Vt);
  for (int cb = 0; cb < NB; cb += Bc) {
    int tiles = Bc / 128;
    k1_gemm<<<NF * tiles, 256, 0, stream>>>(x, w, Vt, E, lin, cb, tiles);
    k2_pair<<<Bc / 4, 256, 0, stream>>>(E, lin, out, cb);
  }
}